// Round 10
// baseline (496.082 us; speedup 1.0000x reference)
//
#include <hip/hip_runtime.h>
#include <math.h>

#define TOKENS 4096
#define BATCH 64

typedef __attribute__((ext_vector_type(8))) short bf16x8;
typedef __attribute__((ext_vector_type(4))) float f32x4;
union U4B { uint4 u; bf16x8 b; };
union U2x2B { uint2 u[2]; bf16x8 b; };

__device__ __forceinline__ float wsum(float v) {
#pragma unroll
  for (int m = 32; m >= 1; m >>= 1) v += __shfl_xor(v, m);
  return v;
}
__device__ __forceinline__ unsigned short f2bf(float f) {
  unsigned u = __float_as_uint(f);
  u += 0x7fffu + ((u >> 16) & 1u);
  return (unsigned short)(u >> 16);
}
__device__ __forceinline__ float bflo(unsigned p) { return __uint_as_float(p << 16); }
__device__ __forceinline__ float bfhi(unsigned p) { return __uint_as_float(p & 0xffff0000u); }
__device__ __forceinline__ float sigmf(float x) { return 1.f / (1.f + expf(-x)); }

// ================= K_PRE: LN->x  |  weight transposes ==========
__global__ __launch_bounds__(256) void k_pre(
    const float* __restrict__ in, const float* __restrict__ lin_g,
    const float* __restrict__ lin_b, unsigned* __restrict__ x,
    const float* __restrict__ Wq, const float* __restrict__ Wv,
    const float* __restrict__ Wih, const float* __restrict__ Whh,
    const float* __restrict__ W1, const float* __restrict__ W2,
    float* __restrict__ WqT, float* __restrict__ WvT, float* __restrict__ WihT,
    float* __restrict__ WhhT, float* __restrict__ W1T, float* __restrict__ W2T) {
  int bid = blockIdx.x, tid = threadIdx.x;
  if (bid < 65536) {
    int row = bid * 4 + (tid >> 6);
    int lane = tid & 63;
    const float* p = in + (size_t)row * 256 + lane * 4;
    float4 v = *(const float4*)p;
    float s  = wsum(v.x + v.y + v.z + v.w);
    float sq = wsum(v.x * v.x + v.y * v.y + v.z * v.z + v.w * v.w);
    float mu = s * (1.f / 256.f);
    float var = sq * (1.f / 256.f) - mu * mu;
    float rs = rsqrtf(var + 1e-5f);
    float4 gg = *(const float4*)(lin_g + lane * 4);
    float4 bb = *(const float4*)(lin_b + lane * 4);
    float y0 = (v.x - mu) * rs * gg.x + bb.x;
    float y1 = (v.y - mu) * rs * gg.y + bb.y;
    float y2 = (v.z - mu) * rs * gg.z + bb.z;
    float y3 = (v.w - mu) * rs * gg.w + bb.w;
    uint2 o;
    o.x = (unsigned)f2bf(y0) | ((unsigned)f2bf(y1) << 16);
    o.y = (unsigned)f2bf(y2) | ((unsigned)f2bf(y3) << 16);
    *(uint2*)(x + (size_t)row * 128 + lane * 2) = o;
    return;
  }
  {
    __shared__ float t[32][33];
    int t2 = bid - 65536;
    const float* S; float* D; int R; int tile;
    if (t2 < 64)       { S = Wq;  D = WqT;  R = 256; tile = t2; }
    else if (t2 < 128) { S = Wv;  D = WvT;  R = 256; tile = t2 - 64; }
    else if (t2 < 192) { S = W1;  D = W1T;  R = 256; tile = t2 - 128; }
    else if (t2 < 256) { S = W2;  D = W2T;  R = 256; tile = t2 - 192; }
    else if (t2 < 448) { S = Wih; D = WihT; R = 768; tile = t2 - 256; }
    else               { S = Whh; D = WhhT; R = 768; tile = t2 - 448; }
    int rt = R >> 5;
    int r0 = (tile % rt) * 32, c0 = (tile / rt) * 32;
    int ci = tid & 31, r8 = tid >> 5;
#pragma unroll
    for (int k = 0; k < 4; ++k) {
      int r = r8 + k * 8;
      t[r][ci] = S[(size_t)(r0 + r) * 256 + c0 + ci];
    }
    __syncthreads();
#pragma unroll
    for (int k = 0; k < 4; ++k) {
      int r = r8 + k * 8;
      D[(size_t)(c0 + r) * R + r0 + ci] = t[ci][r];
    }
  }
}

// ========== K_QW0: slot init + first-iteration qw (uses WqT) ==========
__global__ __launch_bounds__(256) void k_qw0(
    const float* __restrict__ smu, const float* __restrict__ slsig,
    const float* __restrict__ noise, const float* __restrict__ lsl_g,
    const float* __restrict__ lsl_b, const float* __restrict__ WqT,
    const float* __restrict__ Wk, float* __restrict__ slots,
    unsigned* __restrict__ qwb) {
  __shared__ float ln[256];
  __shared__ float q[256];
  __shared__ float red[8];
  int n = blockIdx.x, s = blockIdx.y, tid = threadIdx.x;
  int sd = s * 256 + tid;
  float v = smu[sd] + expf(slsig[sd]) * noise[(size_t)n * 2048 + sd];
  slots[(size_t)n * 2048 + sd] = v;
  float ps = wsum(v), pq = wsum(v * v);
  if ((tid & 63) == 0) { red[tid >> 6] = ps; red[4 + (tid >> 6)] = pq; }
  __syncthreads();
  float sum = red[0] + red[1] + red[2] + red[3];
  float sqq = red[4] + red[5] + red[6] + red[7];
  float mu = sum * (1.f / 256.f);
  float var = sqq * (1.f / 256.f) - mu * mu;
  float rs = rsqrtf(var + 1e-5f);
  ln[tid] = (v - mu) * rs * lsl_g[tid] + lsl_b[tid];
  __syncthreads();
  float a = 0.f;
  for (int d = 0; d < 256; ++d) a += ln[d] * WqT[d * 256 + tid];
  q[tid] = a;
  __syncthreads();
  float c = 0.f;
  for (int e = 0; e < 256; ++e) c += q[e] * Wk[(size_t)e * 256 + tid];
  c *= 0.0625f;
  __syncthreads();
  ln[tid] = c;
  __syncthreads();
  if (tid < 128)
    qwb[((size_t)n * 8 + s) * 128 + tid] =
        (unsigned)f2bf(ln[2 * tid]) | ((unsigned)f2bf(ln[2 * tid + 1]) << 16);
}

// ========== K_ATT: flash-style, 256 tokens/block = 4 chunks of 64 ============
// grid (16, 64), 256 threads. Register prefetch of next chunk overlaps
// softmax+PV. Online-rescaled PV accumulator in registers.
// outputs: stats[n][s][16] = (M_run, S_run); axp[n][bk][s][d] unnormalized
__global__ __launch_bounds__(256) void k_att(const unsigned* __restrict__ x,
                                             const unsigned* __restrict__ qwb,
                                             float2* __restrict__ stats,
                                             float* __restrict__ axp) {
  __shared__ unsigned xs[64][130];   // one 64-token chunk (pad 130)
  __shared__ float lsT[64][8];       // [t_local][slot]
  __shared__ float redM[8][4], redS[8][4];
  __shared__ float Mrun[8], Srun[8], scl[8], Mnew[8];
  int bk = blockIdx.x, n = blockIdx.y;
  int tid = threadIdx.x, wv = tid >> 6, l = tid & 63;
  int col = l & 15, g = l >> 4;
  // A-fragments (qw), loaded once
  uint4 a[8];
  {
    const unsigned* ap = qwb + ((size_t)n * 8 + (l & 7)) * 128 + g * 4;
#pragma unroll
    for (int kk = 0; kk < 8; ++kk) a[kk] = *(const uint4*)(ap + kk * 16);
  }
  if (tid < 8) { Mrun[tid] = -3.4e38f; Srun[tid] = 0.f; }
  float acc[8] = {0, 0, 0, 0, 0, 0, 0, 0};
  int lane32 = tid & 31, g8 = tid >> 5;
  const unsigned* base = x + ((size_t)n * 4096 + bk * 256) * 128 + lane32 * 4;
  uint4 st[8];
  // stage chunk 0 into LDS
#pragma unroll
  for (int p = 0; p < 8; ++p)
    st[p] = *(const uint4*)(base + (size_t)(p * 8 + g8) * 128);
#pragma unroll
  for (int p = 0; p < 8; ++p) {
    unsigned* dr = &xs[p * 8 + g8][lane32 * 4];
    *(uint2*)dr = make_uint2(st[p].x, st[p].y);
    *(uint2*)(dr + 2) = make_uint2(st[p].z, st[p].w);
  }
  __syncthreads();
  int s = tid & 7, tg = tid >> 3;  // tg 0..31
  for (int c = 0; c < 4; ++c) {
    // prefetch next chunk into registers (hidden under QK^T+softmax+PV)
    if (c < 3) {
      const unsigned* src = base + (size_t)(c + 1) * 64 * 128;
#pragma unroll
      for (int p = 0; p < 8; ++p)
        st[p] = *(const uint4*)(src + (size_t)(p * 8 + g8) * 128);
    }
    // QK^T via MFMA; wave wv covers tokens [wv*16, wv*16+16)
    {
      int t0 = wv * 16;
      const unsigned* xr = &xs[t0 + col][0];
      f32x4 qacc = {0.f, 0.f, 0.f, 0.f};
#pragma unroll
      for (int kk = 0; kk < 8; ++kk) {
        U4B aa; aa.u = a[kk];
        U2x2B bb;
        bb.u[0] = *(const uint2*)(xr + kk * 16 + g * 4);
        bb.u[1] = *(const uint2*)(xr + kk * 16 + g * 4 + 2);
        qacc = __builtin_amdgcn_mfma_f32_16x16x32_bf16(aa.b, bb.b, qacc, 0, 0, 0);
      }
      if (g < 2) {
#pragma unroll
        for (int r = 0; r < 4; ++r) lsT[t0 + col][g * 4 + r] = qacc[r];
      }
    }
    __syncthreads();
    // local max per slot
    float l0 = lsT[tg][s], l1 = lsT[tg + 32][s];
    {
      float M = fmaxf(l0, l1);
      M = fmaxf(M, __shfl_xor(M, 8));
      M = fmaxf(M, __shfl_xor(M, 16));
      M = fmaxf(M, __shfl_xor(M, 32));
      if (l < 8) redM[s][wv] = M;
    }
    __syncthreads();
    if (tid < 8) {
      float Mc = fmaxf(fmaxf(redM[tid][0], redM[tid][1]),
                       fmaxf(redM[tid][2], redM[tid][3]));
      float Mn = fmaxf(Mrun[tid], Mc);
      scl[tid] = expf(Mrun[tid] - Mn);
      Mnew[tid] = Mn;
      Mrun[tid] = Mn;
    }
    __syncthreads();
    // exp(l - M_new) into lsT + local sum
    {
      float Mn = Mnew[s];
      float e0 = expf(l0 - Mn), e1 = expf(l1 - Mn);
      lsT[tg][s] = e0;
      lsT[tg + 32][s] = e1;
      float S = e0 + e1;
      S += __shfl_xor(S, 8);
      S += __shfl_xor(S, 16);
      S += __shfl_xor(S, 32);
      if (l < 8) redS[s][wv] = S;
    }
    __syncthreads();
    if (tid < 8) {
      float Sc = redS[tid][0] + redS[tid][1] + redS[tid][2] + redS[tid][3];
      Srun[tid] = Srun[tid] * scl[tid] + Sc;
    }
    // PV on VALU; thread owns column d = tid; rescale + accumulate
    {
      int d = tid;
      float pv[8] = {0, 0, 0, 0, 0, 0, 0, 0};
#pragma unroll 8
      for (int t = 0; t < 64; ++t) {
        unsigned pw = xs[t][d >> 1];
        float xv = (d & 1) ? bfhi(pw) : bflo(pw);
        float4 a0 = *(const float4*)&lsT[t][0];
        float4 a1 = *(const float4*)&lsT[t][4];
        pv[0] += a0.x * xv; pv[1] += a0.y * xv;
        pv[2] += a0.z * xv; pv[3] += a0.w * xv;
        pv[4] += a1.x * xv; pv[5] += a1.y * xv;
        pv[6] += a1.z * xv; pv[7] += a1.w * xv;
      }
#pragma unroll
      for (int ss = 0; ss < 8; ++ss) acc[ss] = acc[ss] * scl[ss] + pv[ss];
    }
    __syncthreads();
    // commit staged chunk to LDS
    if (c < 3) {
#pragma unroll
      for (int p = 0; p < 8; ++p) {
        unsigned* dr = &xs[p * 8 + g8][lane32 * 4];
        *(uint2*)dr = make_uint2(st[p].x, st[p].y);
        *(uint2*)(dr + 2) = make_uint2(st[p].z, st[p].w);
      }
      __syncthreads();
    }
  }
  if (tid < 8)
    stats[((size_t)n * 8 + tid) * 16 + bk] = make_float2(Mrun[tid], Srun[tid]);
  {
    float* op = axp + (((size_t)n * 16 + bk) * 8) * 256 + tid;
#pragma unroll
    for (int ss = 0; ss < 8; ++ss) op[ss * 256] = acc[ss];
  }
}

// ========== K_UPDATE3: combine 16 partials, Wv, GRU, LN, MLP (+ next qw) =====
__global__ __launch_bounds__(512) void k_update3(
    const float* __restrict__ axp, const float2* __restrict__ stats,
    const float* __restrict__ slots_in,
    const float* __restrict__ WvT, const float* __restrict__ WihT,
    const float* __restrict__ WhhT, const float* __restrict__ b_ih,
    const float* __restrict__ b_hh, const float* __restrict__ W1T,
    const float* __restrict__ b1, const float* __restrict__ W2T,
    const float* __restrict__ b2, const float* __restrict__ lml_g,
    const float* __restrict__ lml_b, const float* __restrict__ lsl_g,
    const float* __restrict__ lsl_b, const float* __restrict__ WqT,
    const float* __restrict__ Wk, unsigned* __restrict__ qwb, int doQw,
    float* __restrict__ slots_out) {
  __shared__ float ax[4][256];
  __shared__ float sp[4][256];
  __shared__ float upd[4][256];
  __shared__ float gi[4][768];
  __shared__ float gh[4][768];
  __shared__ float sn[4][256];
  __shared__ float lnv[4][256];
  __shared__ float hid[4][256];
  __shared__ float red[16];
  __shared__ float wch[4][16];
  __shared__ float inv4[4];
  int n = blockIdx.x, sg = blockIdx.y * 4;
  int tid = threadIdx.x;
  if (tid < 4) {
    const float2* st = stats + ((size_t)n * 8 + sg + tid) * 16;
    float M = -3.4e38f;
#pragma unroll
    for (int c = 0; c < 16; ++c) M = fmaxf(M, st[c].x);
    float S = 0.f;
#pragma unroll
    for (int c = 0; c < 16; ++c) {
      float w = expf(st[c].x - M);
      wch[tid][c] = w;
      S += w * st[c].y;
    }
    inv4[tid] = 1.f / (S * (1.f + 1e-8f));
  }
  __syncthreads();
  for (int i = tid; i < 1024; i += 512) {
    int sl = i >> 8, d = i & 255;
    const float* pp = axp + (size_t)n * 32768 + (sg + sl) * 256 + d;
    float a = 0.f;
#pragma unroll
    for (int c = 0; c < 16; ++c) a += wch[sl][c] * pp[(size_t)c * 2048];
    ax[sl][d] = a * inv4[sl];
    sp[sl][d] = slots_in[((size_t)n * 8 + sg + sl) * 256 + d];
  }
  __syncthreads();
  int e = tid & 255, h = tid >> 8;
  {
    float a0 = 0.f, a1 = 0.f;
    for (int d = 0; d < 256; ++d) {
      float w = WvT[d * 256 + e];
      a0 += ax[h * 2][d] * w;
      a1 += ax[h * 2 + 1][d] * w;
    }
    upd[h * 2][e] = a0;
    upd[h * 2 + 1][e] = a1;
  }
  __syncthreads();
  for (int jj = tid; jj < 1536; jj += 512) {
    bool ihs = jj < 768;
    int j = ihs ? jj : jj - 768;
    const float* WT = ihs ? WihT : WhhT;
    const float* src = ihs ? &upd[0][0] : &sp[0][0];
    float a0 = 0.f, a1 = 0.f, a2 = 0.f, a3 = 0.f;
    for (int d = 0; d < 256; ++d) {
      float w = WT[(size_t)d * 768 + j];
      a0 += src[d] * w;
      a1 += src[256 + d] * w;
      a2 += src[512 + d] * w;
      a3 += src[768 + d] * w;
    }
    float bb = ihs ? b_ih[j] : b_hh[j];
    float* dst = ihs ? &gi[0][0] : &gh[0][0];
    dst[j] = a0 + bb;
    dst[768 + j] = a1 + bb;
    dst[1536 + j] = a2 + bb;
    dst[2304 + j] = a3 + bb;
  }
  __syncthreads();
  for (int i = tid; i < 1024; i += 512) {
    int sl = i >> 8, j = i & 255;
    float r = sigmf(gi[sl][j] + gh[sl][j]);
    float z = sigmf(gi[sl][j + 256] + gh[sl][j + 256]);
    float hh = tanhf(gi[sl][j + 512] + r * gh[sl][j + 512]);
    sn[sl][j] = (1.f - z) * hh + z * sp[sl][j];
  }
  __syncthreads();
  {
    int sl = tid >> 7, qq = tid & 127;
    float v0 = sn[sl][qq], v1 = sn[sl][qq + 128];
    float ps = wsum(v0 + v1);
    float pq = wsum(v0 * v0 + v1 * v1);
    int wid = tid >> 6;
    if ((tid & 63) == 0) { red[wid] = ps; red[8 + wid] = pq; }
    __syncthreads();
    float ssum = red[sl * 2] + red[sl * 2 + 1];
    float sqq  = red[8 + sl * 2] + red[8 + sl * 2 + 1];
    float mu = ssum * (1.f / 256.f);
    float var = sqq * (1.f / 256.f) - mu * mu;
    float rs = rsqrtf(var + 1e-5f);
    lnv[sl][qq]       = (v0 - mu) * rs * lml_g[qq] + lml_b[qq];
    lnv[sl][qq + 128] = (v1 - mu) * rs * lml_g[qq + 128] + lml_b[qq + 128];
  }
  __syncthreads();
  {
    float a0 = 0.f, a1 = 0.f;
    for (int d = 0; d < 256; ++d) {
      float w = W1T[d * 256 + e];
      a0 += lnv[h * 2][d] * w;
      a1 += lnv[h * 2 + 1][d] * w;
    }
    hid[h * 2][e]     = fmaxf(a0 + b1[e], 0.f);
    hid[h * 2 + 1][e] = fmaxf(a1 + b1[e], 0.f);
  }
  __syncthreads();
  {
    float a0 = 0.f, a1 = 0.f;
    for (int d = 0; d < 256; ++d) {
      float w = W2T[d * 256 + e];
      a0 += hid[h * 2][d] * w;
      a1 += hid[h * 2 + 1][d] * w;
    }
    float o0 = sn[h * 2][e] + a0 + b2[e];
    float o1 = sn[h * 2 + 1][e] + a1 + b2[e];
    slots_out[((size_t)n * 8 + sg + h * 2) * 256 + e]     = o0;
    slots_out[((size_t)n * 8 + sg + h * 2 + 1) * 256 + e] = o1;
    ax[h * 2][e] = o0;
    ax[h * 2 + 1][e] = o1;
  }
  if (!doQw) return;
  __syncthreads();
  {
    int sl = tid >> 7, qq = tid & 127;
    float v0 = ax[sl][qq], v1 = ax[sl][qq + 128];
    float ps = wsum(v0 + v1);
    float pq = wsum(v0 * v0 + v1 * v1);
    int wid = tid >> 6;
    if ((tid & 63) == 0) { red[wid] = ps; red[8 + wid] = pq; }
    __syncthreads();
    float ssum = red[sl * 2] + red[sl * 2 + 1];
    float sqq  = red[8 + sl * 2] + red[8 + sl * 2 + 1];
    float mu = ssum * (1.f / 256.f);
    float var = sqq * (1.f / 256.f) - mu * mu;
    float rs = rsqrtf(var + 1e-5f);
    sp[sl][qq]       = (v0 - mu) * rs * lsl_g[qq] + lsl_b[qq];
    sp[sl][qq + 128] = (v1 - mu) * rs * lsl_g[qq + 128] + lsl_b[qq + 128];
  }
  __syncthreads();
  {
    float a0 = 0.f, a1 = 0.f;
    for (int d = 0; d < 256; ++d) {
      float w = WqT[d * 256 + e];
      a0 += sp[h * 2][d] * w;
      a1 += sp[h * 2 + 1][d] * w;
    }
    upd[h * 2][e] = a0;
    upd[h * 2 + 1][e] = a1;
  }
  __syncthreads();
  {
    float c0 = 0.f, c1 = 0.f;
    for (int ee = 0; ee < 256; ++ee) {
      float w = Wk[(size_t)ee * 256 + e];
      c0 += upd[h * 2][ee] * w;
      c1 += upd[h * 2 + 1][ee] * w;
    }
    hid[h * 2][e]     = c0 * 0.0625f;
    hid[h * 2 + 1][e] = c1 * 0.0625f;
  }
  __syncthreads();
  {
    int sl = tid >> 7, p = tid & 127;
    qwb[((size_t)n * 8 + sg + sl) * 128 + p] =
        (unsigned)f2bf(hid[sl][2 * p]) | ((unsigned)f2bf(hid[sl][2 * p + 1]) << 16);
  }
}

extern "C" void kernel_launch(void* const* d_in, const int* in_sizes, int n_in,
                              void* d_out, int out_size, void* d_ws, size_t ws_size,
                              hipStream_t stream) {
  (void)in_sizes; (void)n_in; (void)out_size; (void)ws_size;
  const float* inputs = (const float*)d_in[0];
  const float* noise  = (const float*)d_in[1];
  const float* smu    = (const float*)d_in[2];
  const float* slsig  = (const float*)d_in[3];
  const float* Wq     = (const float*)d_in[4];
  const float* Wk     = (const float*)d_in[5];
  const float* Wv     = (const float*)d_in[6];
  const float* W_ih   = (const float*)d_in[7];
  const float* W_hh   = (const float*)d_in[8];
  const float* b_ih   = (const float*)d_in[9];
  const float* b_hh   = (const float*)d_in[10];
  const float* W1     = (const float*)d_in[11];
  const float* b1     = (const float*)d_in[12];
  const float* W2     = (const float*)d_in[13];
  const float* b2     = (const float*)d_in[14];
  const float* lin_g  = (const float*)d_in[15];
  const float* lin_b  = (const float*)d_in[16];
  const float* lsl_g  = (const float*)d_in[17];
  const float* lsl_b  = (const float*)d_in[18];
  const float* lml_g  = (const float*)d_in[19];
  const float* lml_b  = (const float*)d_in[20];
  float* out = (float*)d_out;
  char* ws = (char*)d_ws;
  unsigned* x    = (unsigned*)(ws + 0);            // 134217728
  unsigned* qwb  = (unsigned*)(ws + 134217728);    // 262144
  float2* stats  = (float2*)(ws + 134479872);      // 65536
  float* axp     = (float*)(ws + 134545408);       // 8388608
  float* WqT     = (float*)(ws + 142934016);       // 262144
  float* WvT     = (float*)(ws + 143196160);       // 262144
  float* WihT    = (float*)(ws + 143458304);       // 786432
  float* WhhT    = (float*)(ws + 144244736);       // 786432
  float* W1T     = (float*)(ws + 145031168);       // 262144
  float* W2T     = (float*)(ws + 145293312);       // 262144

  k_pre<<<dim3(66176), 256, 0, stream>>>(inputs, lin_g, lin_b, x,
                                         Wq, Wv, W_ih, W_hh, W1, W2,
                                         WqT, WvT, WihT, WhhT, W1T, W2T);
  k_qw0<<<dim3(BATCH, 8), 256, 0, stream>>>(smu, slsig, noise, lsl_g, lsl_b,
                                            WqT, Wk, out, qwb);
  for (int it = 0; it < 3; ++it) {
    k_att<<<dim3(16, BATCH), 256, 0, stream>>>(x, qwb, stats, axp);
    k_update3<<<dim3(BATCH, 2), 512, 0, stream>>>(
        axp, stats, out, WvT, WihT, WhhT, b_ih, b_hh, W1T, b1, W2T, b2,
        lml_g, lml_b, lsl_g, lsl_b, WqT, Wk, qwb, (it < 2) ? 1 : 0, out);
  }
}